// Round 8
// baseline (235.784 us; speedup 1.0000x reference)
//
#include <hip/hip_runtime.h>

#define T_SEQ 2048
#define DHEAD 128
#define NBH 16
#define SCALE 0.08838834764831845f

typedef unsigned short u16;
typedef unsigned int u32;
typedef u16 u16x4 __attribute__((ext_vector_type(4)));
typedef u16 u16x8 __attribute__((ext_vector_type(8)));
typedef u32 u32x2 __attribute__((ext_vector_type(2)));
typedef short s16x4 __attribute__((ext_vector_type(4)));
typedef __bf16 bf16x8 __attribute__((ext_vector_type(8)));
typedef float f32x4 __attribute__((ext_vector_type(4)));

__device__ __forceinline__ u16 f2bfu(float x) {
  union { float f; unsigned u; } c; c.f = x;
  unsigned u = c.u;
  u = u + 0x7FFFu + ((u >> 16) & 1u);   // RNE
  return (u16)(u >> 16);
}

__device__ __forceinline__ bf16x8 ldsFrag(const u16* p) {
  u16x8 t = *(const u16x8*)p;
  return __builtin_bit_cast(bf16x8, t);
}

__device__ __forceinline__ f32x4 mfma16x16x16bf16(s16x4 a, s16x4 b, f32x4 c) {
#if __has_builtin(__builtin_amdgcn_mfma_f32_16x16x16bf16_1k)
  return __builtin_amdgcn_mfma_f32_16x16x16bf16_1k(a, b, c, 0, 0, 0);
#else
  asm("v_mfma_f32_16x16x16_bf16 %0, %1, %2, %0" : "+v"(c) : "v"(a), "v"(b));
  return c;
#endif
}

__device__ __forceinline__ void gld_lds16(const void* g, void* l) {
  __builtin_amdgcn_global_load_lds(
      (__attribute__((address_space(1))) const unsigned int*)g,
      (__attribute__((address_space(3))) unsigned int*)l, 16, 0, 0);
}

// ---------------------------------------------------------------------------
// Gate scan: fc=cumsum(logsigmoid(f)); a=i-fc; c=cummax(a).
// ---------------------------------------------------------------------------
__global__ __launch_bounds__(1024) void gate_scan_kernel(
    const float* __restrict__ ig, const float* __restrict__ fg,
    float* __restrict__ a_out, float* __restrict__ c_out,
    float* __restrict__ fc_out)
{
  const int bh = blockIdx.x, tid = threadIdx.x;
  const int w = tid >> 6, lane = tid & 63;
  const int base = bh * T_SEQ + tid * 2;
  __shared__ float wsum[16];
  __shared__ float wmax[16];

  const float x0 = fg[base], x1 = fg[base + 1];
  const float ls0 = fminf(x0, 0.f) - log1pf(expf(-fabsf(x0)));
  const float ls1 = fminf(x1, 0.f) - log1pf(expf(-fabsf(x1)));
  const float s = ls0 + ls1;

  float sc = s;
#pragma unroll
  for (int off = 1; off < 64; off <<= 1) {
    const float t = __shfl_up(sc, off, 64);
    if (lane >= off) sc += t;
  }
  if (lane == 63) wsum[w] = sc;
  __syncthreads();
  float wo = 0.f;
#pragma unroll
  for (int i = 0; i < 15; ++i) if (i < w) wo += wsum[i];
  const float excl = wo + (sc - s);
  const float fc0 = excl + ls0;
  const float fc1 = excl + ls0 + ls1;
  fc_out[base] = fc0; fc_out[base + 1] = fc1;
  const float a0 = ig[base] - fc0;
  const float a1 = ig[base + 1] - fc1;
  a_out[base] = a0; a_out[base + 1] = a1;

  const float m = fmaxf(a0, a1);
  float mc = m;
#pragma unroll
  for (int off = 1; off < 64; off <<= 1) {
    const float t = __shfl_up(mc, off, 64);
    if (lane >= off) mc = fmaxf(mc, t);
  }
  if (lane == 63) wmax[w] = mc;
  __syncthreads();
  float wmo = -INFINITY;
#pragma unroll
  for (int i = 0; i < 15; ++i) if (i < w) wmo = fmaxf(wmo, wmax[i]);
  const float prev = __shfl_up(mc, 1, 64);
  float exclm = (lane > 0) ? prev : -INFINITY;
  exclm = fmaxf(exclm, wmo);
  c_out[base] = fmaxf(exclm, a0);
  c_out[base + 1] = fmaxf(exclm, m);
}

// ---------------------------------------------------------------------------
// Fused pre-pass: K_hat = K*exp(a-c_end) fp32->bf16; V -> bf16 Vt transposed.
// ---------------------------------------------------------------------------
__global__ __launch_bounds__(256) void cvt_kv_kernel(
    const float* __restrict__ kk, const float* __restrict__ v,
    const float* __restrict__ ag, const float* __restrict__ cg,
    u16* __restrict__ kbf, u16* __restrict__ vt)
{
  const int bh = blockIdx.y, kt = blockIdx.x, tid = threadIdx.x;
  // ---- K part ----
  {
    const int r = tid >> 2;                 // 0..63
    const int c0 = (tid & 3) * 32;
    const int row = kt * 64 + r;
    const float sc = __expf(ag[bh * T_SEQ + row] - cg[bh * T_SEQ + (row | 63)]);
    const float* sp = kk + ((size_t)bh * T_SEQ + row) * DHEAD + c0;
    u16* dp = kbf + ((size_t)bh * T_SEQ + row) * DHEAD + c0;
#pragma unroll
    for (int j = 0; j < 8; ++j) {
      const float4 x = *(const float4*)(sp + j * 4);
      u16x4 pq;
      pq[0] = f2bfu(x.x * sc); pq[1] = f2bfu(x.y * sc);
      pq[2] = f2bfu(x.z * sc); pq[3] = f2bfu(x.w * sc);
      *(u16x4*)(dp + j * 4) = pq;
    }
  }
  // ---- V transpose part ----
  __shared__ __align__(16) u16 L[128 * 72];
  const int n0 = (tid & 31) * 4, k0 = (tid >> 5) * 8;
  const float* vp = v + ((size_t)bh * T_SEQ + kt * 64 + k0) * DHEAD + n0;
  u16 tv[4][8];
#pragma unroll
  for (int rr = 0; rr < 8; ++rr) {
    const float4 x = *(const float4*)(vp + rr * DHEAD);
    tv[0][rr] = f2bfu(x.x); tv[1][rr] = f2bfu(x.y);
    tv[2][rr] = f2bfu(x.z); tv[3][rr] = f2bfu(x.w);
  }
#pragma unroll
  for (int j = 0; j < 4; ++j) {
    u16x8 pq;
#pragma unroll
    for (int rr = 0; rr < 8; ++rr) pq[rr] = tv[j][rr];
    *(u16x8*)(&L[(n0 + j) * 72 + k0]) = pq;
  }
  __syncthreads();
  const int row = tid >> 1, s0 = (tid & 1) * 32;
  u16* op = vt + ((size_t)bh * DHEAD + row) * T_SEQ + kt * 64 + s0;
#pragma unroll
  for (int i = 0; i < 4; ++i)
    *(u16x8*)(op + i * 8) = *(const u16x8*)(&L[row * 72 + s0 + i * 8]);
}

// ---------------------------------------------------------------------------
// Main flash mLSTM.  256 blocks x 1024 thr (16 waves = 4/SIMD).
// R1 skeleton (proven 54us, no spill): UNIFORM 33-iteration schedule
// (tile A=31-p stages 0..31-p, then tile B=p stages 0..p), wave =
// kg(4 key-groups of 16) x rq(4 row-quarters of 16), 2-slot ping-pong.
// NEW vs R1 (attack the CU-shared LDS/DMA serializer, the ~4000 cyc/stage
// constant measured across R0/R1/R4/R7):
//   1. V is NOT staged through LDS at all: PV A-frags load direct
//      global->register from vtbf (8B/lane, 32B contiguous per vd row;
//      16KB stage slice is L1/L2-resident).  Halves gld_lds DMA bytes
//      (32->16 KB/stage), halves LDS reads (128->64 KB/stage), removes
//      all V-side bank conflicts.
//   2. cg[] per-stage scalar load replaced by one preloaded lane-indexed
//      register + __shfl (no memory op on the per-stage critical path).
// LDS: K dbuf 2x16KB @0; osh 64x132 f32 @32768; rsh @66560 (67.6 KB).
// ---------------------------------------------------------------------------
template <bool FAST>
__global__ __launch_bounds__(1024, 4) void mlstm_fwd_kernel(
    const float* __restrict__ qg, const float* __restrict__ kxg,
    const float* __restrict__ vg,
    const u16* __restrict__ kbf, const u16* __restrict__ vtbf,
    const float* __restrict__ ag, const float* __restrict__ cg,
    const float* __restrict__ fcg, float* __restrict__ out)
{
  const int bx = (int)blockIdx.x;
  const int bh = bx & 15, p = bx >> 4;
  const int tid = (int)threadIdx.x;
  const int w = tid >> 6, lane = tid & 63;
  const int quad = lane >> 4, l16 = lane & 15;
  const int kg = w & 3, rq = w >> 2;

  const int qtA = 31 - p, qtB = p;
  const int nA = qtA + 1;                 // nA + (qtB+1) == 33 for all p

  // LDS: K dbuf 2x16KB @0; osh 64x132 f32 @32768 (33792B); rsh @66560.
  __shared__ __align__(16) unsigned char SM[67584];
  u16* Kst = (u16*)SM;
  float* osh = (float*)(SM + 32768);
  float* rsh = (float*)(SM + 66560);

  const size_t hoff = (size_t)bh * T_SEQ * DHEAD;
  const int goff = bh * T_SEQ;

  // per-tile gate max, lane-indexed: cgl[lane] = cg end of tile (lane&31)
  const float cgl = cg[goff + (lane & 31) * 64 + 63];

  // Q -> B-frags qf[kc]: B[k=quad*8+j][n=l16], row = qt*64 + rq*16 + l16
  bf16x8 qf[4];
  auto loadQ = [&](int lqt) {
    const float* qp = qg + hoff + (size_t)(lqt * 64 + rq * 16 + l16) * DHEAD + quad * 8;
#pragma unroll
    for (int kc = 0; kc < 4; ++kc) {
      const float4 x0 = *(const float4*)(qp + kc * 32);
      const float4 x1 = *(const float4*)(qp + kc * 32 + 4);
      u16x8 t;
      t[0] = f2bfu(x0.x); t[1] = f2bfu(x0.y); t[2] = f2bfu(x0.z); t[3] = f2bfu(x0.w);
      t[4] = f2bfu(x1.x); t[5] = f2bfu(x1.y); t[6] = f2bfu(x1.z); t[7] = f2bfu(x1.w);
      qf[kc] = __builtin_bit_cast(bf16x8, t);
    }
  };

  f32x4 oa[8];                           // O^T partial: 8 vd-tiles x 16 rows
  float rsacc;
  auto zeroAcc = [&]() {
#pragma unroll
    for (int mt = 0; mt < 8; ++mt) oa[mt] = (f32x4){0.f, 0.f, 0.f, 0.f};
    rsacc = 0.f;
  };
  zeroAcc();

  // ---- K staging (LDS via DMA), loop-invariant addresses ----
  const int skey = tid >> 4, sdb = (tid & 15) ^ (skey & 7);
  const u16* ksBase = kbf + (size_t)goff * DHEAD + (size_t)skey * DHEAD + sdb * 8;

  auto stage = [&](int st, int b) {            // K only: 16 KB/stage
    u16* KbL = Kst + b * 8192;
    if (FAST) {
      gld_lds16(ksBase + (size_t)st * 64 * DHEAD, KbL + w * 512);
    } else {
      const float ct = cg[goff + st * 64 + 63];
      const float* kp = kxg + hoff + (size_t)(st * 64 + skey) * DHEAD + sdb * 8;
      const float scv = __expf(ag[goff + st * 64 + skey] - ct);
      const float4 x0 = *(const float4*)kp;
      const float4 x1 = *(const float4*)(kp + 4);
      u16x8 pk;
      pk[0] = f2bfu(x0.x * scv); pk[1] = f2bfu(x0.y * scv);
      pk[2] = f2bfu(x0.z * scv); pk[3] = f2bfu(x0.w * scv);
      pk[4] = f2bfu(x1.x * scv); pk[5] = f2bfu(x1.y * scv);
      pk[6] = f2bfu(x1.z * scv); pk[7] = f2bfu(x1.w * scv);
      *(u16x8*)(KbL + tid * 8) = pk;
    }
  };

  const int keyA = kg * 16 + l16;         // A-frag key row (QK)
  const int ksw  = l16 & 7;
  // V direct-global per-thread base: vd=l16 (+16*mt), key = kg*16+quad*4 (+st*64)
  const u16* vTh = vtbf + (size_t)bh * DHEAD * T_SEQ + (size_t)l16 * T_SEQ
                 + kg * 16 + quad * 4;

  auto computeStage = [&](int cqt, int st, int b, float ccmax) {
    const u16* KbL = Kst + b * 8192;

    // ---- S^T = K_hat Q^T ----
    f32x4 sa = (f32x4){0.f, 0.f, 0.f, 0.f};
#pragma unroll
    for (int kc = 0; kc < 4; ++kc) {
      const bf16x8 kf = ldsFrag(KbL + keyA * 128 + (((kc * 4 + quad) ^ ksw) * 8));
      sa = __builtin_amdgcn_mfma_f32_16x16x32_bf16(kf, qf[kc], sa, 0, 0, 0);
    }

    const float ct = __shfl(cgl, st, 64);
    const float etile = SCALE * __expf(ct - ccmax);
    float x0 = sa[0] * etile, x1 = sa[1] * etile;
    float x2 = sa[2] * etile, x3 = sa[3] * etile;
    if (st == cqt) {
      const int qr = rq * 16 + l16, kb0 = kg * 16 + quad * 4;
      if (kb0 + 0 > qr) x0 = 0.f;
      if (kb0 + 1 > qr) x1 = 0.f;
      if (kb0 + 2 > qr) x2 = 0.f;
      if (kb0 + 3 > qr) x3 = 0.f;
    }
    rsacc += (x0 + x1) + (x2 + x3);
    u32 plo, phi;
    asm("v_cvt_pk_bf16_f32 %0, %1, %2" : "=v"(plo) : "v"(x0), "v"(x1));
    asm("v_cvt_pk_bf16_f32 %0, %1, %2" : "=v"(phi) : "v"(x2), "v"(x3));
    const s16x4 pfr = __builtin_bit_cast(s16x4, (u32x2){plo, phi});

    // ---- O^T += V^T P^T ----  (V direct from global; L1/L2-resident slice)
    const u16* vSt = vTh + st * 64;
#pragma unroll
    for (int mt = 0; mt < 8; ++mt) {
      s16x4 va;
      if (FAST) {
        va = *(const s16x4*)(vSt + (size_t)mt * 16 * T_SEQ);
      } else {
        const int kb = st * 64 + kg * 16 + quad * 4;
        const int vd = mt * 16 + l16;
        u16x4 tv;
#pragma unroll
        for (int j = 0; j < 4; ++j)
          tv[j] = f2bfu(vg[hoff + (size_t)(kb + j) * DHEAD + vd]);
        va = __builtin_bit_cast(s16x4, tv);
      }
      oa[mt] = mfma16x16x16bf16(va, pfr, oa[mt]);
    }
  };

  auto epilogue = [&](int eqt, float ecmax) {
    // rowsum: reduce across quads (keys), combine key-groups via LDS
    float x = rsacc;
    x += __shfl_xor(x, 16, 64);
    x += __shfl_xor(x, 32, 64);
    if (lane < 16) rsh[kg * 64 + rq * 16 + lane] = x;
    __syncthreads();
    float inv = 0.f;
    if (kg == 3) {
      const int row = rq * 16 + l16;
      const float tot = rsh[row] + rsh[64 + row] + rsh[128 + row] + rsh[192 + row];
      const float nf = __expf(-(ecmax + fcg[goff + eqt * 64 + row]));
      inv = 1.f / fmaxf(fabsf(tot), nf);
    }
    // 4-round partial-O combine over kg (float4, stride 132)
    for (int r = 0; r < 4; ++r) {
      if (kg == r) {
        const int row = rq * 16 + l16;
#pragma unroll
        for (int mt = 0; mt < 8; ++mt) {
          float* ap = osh + row * 132 + mt * 16 + quad * 4;
          f32x4 vv = oa[mt];
          if (r > 0) vv = vv + *(const f32x4*)ap;
          if (r == 3) vv = vv * inv;
          *(f32x4*)ap = vv;
        }
      }
      __syncthreads();
    }
    // cooperative coalesced store
    const int col = tid & 31, r0 = tid >> 5;
#pragma unroll
    for (int i = 0; i < 2; ++i) {
      const int row = r0 + 32 * i;
      const f32x4 vv = *(const f32x4*)(osh + row * 132 + col * 4);
      *(f32x4*)(out + hoff + (size_t)(eqt * 64 + row) * DHEAD + col * 4) = vv;
    }
    __syncthreads();
  };

  // -------- prologue --------
  int qt = qtA;
  float cmax = __shfl(cgl, qtA, 64);
  loadQ(qtA);
  stage(0, 0);
  __syncthreads();

  // -------- 33 uniform iterations --------
  for (int it = 0; it < 33; ++it) {
    if (it < 32) {
      const int nx = it + 1;
      stage(nx < nA ? nx : nx - nA, nx & 1);
    }
    computeStage(qt, (it < nA) ? it : it - nA, it & 1, cmax);
    __syncthreads();
    if (it == nA - 1) {
      loadQ(qtB);                  // qf is only 16 regs: safe co-live (R1)
      epilogue(qtA, cmax);
      zeroAcc();
      qt = qtB;
      cmax = __shfl(cgl, qtB, 64);
    }
  }
  epilogue(qtB, cmax);
}

// ---------------------------------------------------------------------------
extern "C" void kernel_launch(void* const* d_in, const int* in_sizes, int n_in,
                              void* d_out, int out_size, void* d_ws, size_t ws_size,
                              hipStream_t stream) {
  const float* q  = (const float*)d_in[0];
  const float* k  = (const float*)d_in[1];
  const float* v  = (const float*)d_in[2];
  const float* ig = (const float*)d_in[3];
  const float* fg = (const float*)d_in[4];

  const size_t gate_bytes = (size_t)3 * NBH * T_SEQ * sizeof(float);
  const size_t kv_elems   = (size_t)NBH * T_SEQ * DHEAD;
  const bool fast = ws_size >= gate_bytes + 2 * kv_elems * sizeof(u16);

  float* a_ws  = (float*)d_ws;
  float* c_ws  = a_ws + NBH * T_SEQ;
  float* fc_ws = c_ws + NBH * T_SEQ;
  u16* kbf  = (u16*)((char*)d_ws + gate_bytes);
  u16* vtbf = kbf + kv_elems;

  gate_scan_kernel<<<dim3(NBH), dim3(1024), 0, stream>>>(ig, fg, a_ws, c_ws, fc_ws);
  if (fast) {
    cvt_kv_kernel<<<dim3(T_SEQ / 64, NBH), dim3(256), 0, stream>>>(
        k, v, a_ws, c_ws, kbf, vtbf);
    mlstm_fwd_kernel<true><<<dim3(256), dim3(1024), 0, stream>>>(
        q, k, v, kbf, vtbf, a_ws, c_ws, fc_ws, (float*)d_out);
  } else {
    mlstm_fwd_kernel<false><<<dim3(256), dim3(1024), 0, stream>>>(
        q, k, v, kbf, vtbf, a_ws, c_ws, fc_ws, (float*)d_out);
  }
}

// Round 9
// 148.066 us; speedup vs baseline: 1.5924x; 1.5924x over previous
//
#include <hip/hip_runtime.h>

#define T_SEQ 2048
#define DHEAD 128
#define NBH 16
#define SCALE 0.08838834764831845f

typedef unsigned short u16;
typedef unsigned int u32;
typedef u16 u16x4 __attribute__((ext_vector_type(4)));
typedef u16 u16x8 __attribute__((ext_vector_type(8)));
typedef u32 u32x2 __attribute__((ext_vector_type(2)));
typedef short s16x4 __attribute__((ext_vector_type(4)));
typedef __bf16 bf16x8 __attribute__((ext_vector_type(8)));
typedef float f32x4 __attribute__((ext_vector_type(4)));

__device__ __forceinline__ u16 f2bfu(float x) {
  union { float f; unsigned u; } c; c.f = x;
  unsigned u = c.u;
  u = u + 0x7FFFu + ((u >> 16) & 1u);   // RNE
  return (u16)(u >> 16);
}

__device__ __forceinline__ bf16x8 ldsFrag(const u16* p) {
  u16x8 t = *(const u16x8*)p;
  return __builtin_bit_cast(bf16x8, t);
}

__device__ __forceinline__ f32x4 mfma16x16x16bf16(s16x4 a, s16x4 b, f32x4 c) {
#if __has_builtin(__builtin_amdgcn_mfma_f32_16x16x16bf16_1k)
  return __builtin_amdgcn_mfma_f32_16x16x16bf16_1k(a, b, c, 0, 0, 0);
#else
  asm("v_mfma_f32_16x16x16_bf16 %0, %1, %2, %0" : "+v"(c) : "v"(a), "v"(b));
  return c;
#endif
}

// ---------------------------------------------------------------------------
// Gate scan: fc=cumsum(logsigmoid(f)); a=i-fc; c=cummax(a).
// ---------------------------------------------------------------------------
__global__ __launch_bounds__(1024) void gate_scan_kernel(
    const float* __restrict__ ig, const float* __restrict__ fg,
    float* __restrict__ a_out, float* __restrict__ c_out,
    float* __restrict__ fc_out)
{
  const int bh = blockIdx.x, tid = threadIdx.x;
  const int w = tid >> 6, lane = tid & 63;
  const int base = bh * T_SEQ + tid * 2;
  __shared__ float wsum[16];
  __shared__ float wmax[16];

  const float x0 = fg[base], x1 = fg[base + 1];
  const float ls0 = fminf(x0, 0.f) - log1pf(expf(-fabsf(x0)));
  const float ls1 = fminf(x1, 0.f) - log1pf(expf(-fabsf(x1)));
  const float s = ls0 + ls1;

  float sc = s;
#pragma unroll
  for (int off = 1; off < 64; off <<= 1) {
    const float t = __shfl_up(sc, off, 64);
    if (lane >= off) sc += t;
  }
  if (lane == 63) wsum[w] = sc;
  __syncthreads();
  float wo = 0.f;
#pragma unroll
  for (int i = 0; i < 15; ++i) if (i < w) wo += wsum[i];
  const float excl = wo + (sc - s);
  const float fc0 = excl + ls0;
  const float fc1 = excl + ls0 + ls1;
  fc_out[base] = fc0; fc_out[base + 1] = fc1;
  const float a0 = ig[base] - fc0;
  const float a1 = ig[base + 1] - fc1;
  a_out[base] = a0; a_out[base + 1] = a1;

  const float m = fmaxf(a0, a1);
  float mc = m;
#pragma unroll
  for (int off = 1; off < 64; off <<= 1) {
    const float t = __shfl_up(mc, off, 64);
    if (lane >= off) mc = fmaxf(mc, t);
  }
  if (lane == 63) wmax[w] = mc;
  __syncthreads();
  float wmo = -INFINITY;
#pragma unroll
  for (int i = 0; i < 15; ++i) if (i < w) wmo = fmaxf(wmo, wmax[i]);
  const float prev = __shfl_up(mc, 1, 64);
  float exclm = (lane > 0) ? prev : -INFINITY;
  exclm = fmaxf(exclm, wmo);
  c_out[base] = fmaxf(exclm, a0);
  c_out[base + 1] = fmaxf(exclm, m);
}

// ---------------------------------------------------------------------------
// Fused pre-pass: K_hat = K*exp(a-c_end) fp32->bf16; V -> bf16 Vt transposed.
// ---------------------------------------------------------------------------
__global__ __launch_bounds__(256) void cvt_kv_kernel(
    const float* __restrict__ kk, const float* __restrict__ v,
    const float* __restrict__ ag, const float* __restrict__ cg,
    u16* __restrict__ kbf, u16* __restrict__ vt)
{
  const int bh = blockIdx.y, kt = blockIdx.x, tid = threadIdx.x;
  // ---- K part ----
  {
    const int r = tid >> 2;                 // 0..63
    const int c0 = (tid & 3) * 32;
    const int row = kt * 64 + r;
    const float sc = __expf(ag[bh * T_SEQ + row] - cg[bh * T_SEQ + (row | 63)]);
    const float* sp = kk + ((size_t)bh * T_SEQ + row) * DHEAD + c0;
    u16* dp = kbf + ((size_t)bh * T_SEQ + row) * DHEAD + c0;
#pragma unroll
    for (int j = 0; j < 8; ++j) {
      const float4 x = *(const float4*)(sp + j * 4);
      u16x4 pq;
      pq[0] = f2bfu(x.x * sc); pq[1] = f2bfu(x.y * sc);
      pq[2] = f2bfu(x.z * sc); pq[3] = f2bfu(x.w * sc);
      *(u16x4*)(dp + j * 4) = pq;
    }
  }
  // ---- V transpose part ----
  __shared__ __align__(16) u16 L[128 * 72];
  const int n0 = (tid & 31) * 4, k0 = (tid >> 5) * 8;
  const float* vp = v + ((size_t)bh * T_SEQ + kt * 64 + k0) * DHEAD + n0;
  u16 tv[4][8];
#pragma unroll
  for (int rr = 0; rr < 8; ++rr) {
    const float4 x = *(const float4*)(vp + rr * DHEAD);
    tv[0][rr] = f2bfu(x.x); tv[1][rr] = f2bfu(x.y);
    tv[2][rr] = f2bfu(x.z); tv[3][rr] = f2bfu(x.w);
  }
#pragma unroll
  for (int j = 0; j < 4; ++j) {
    u16x8 pq;
#pragma unroll
    for (int rr = 0; rr < 8; ++rr) pq[rr] = tv[j][rr];
    *(u16x8*)(&L[(n0 + j) * 72 + k0]) = pq;
  }
  __syncthreads();
  const int row = tid >> 1, s0 = (tid & 1) * 32;
  u16* op = vt + ((size_t)bh * DHEAD + row) * T_SEQ + kt * 64 + s0;
#pragma unroll
  for (int i = 0; i < 4; ++i)
    *(u16x8*)(op + i * 8) = *(const u16x8*)(&L[row * 72 + s0 + i * 8]);
}

// ---------------------------------------------------------------------------
// Main flash mLSTM.  256 blocks x 1024 thr (16 waves = 4/SIMD).
// R1 skeleton (proven 54us): UNIFORM 33-iteration schedule (tile A=31-p
// stages 0..31-p then tile B=p stages 0..p), wave = kg(4)x rq(4),
// 2-slot ping-pong, identical LDS layout and compute.
// ONE CHANGE vs R1: staging is REG-STAGED (T14), not global_load_lds DMA.
//   Measured invariant: ~3900 cyc per 32KB-staged window across R0/R1/R3
//   (and 2x for R7's 64KB) -> hypothesis: per-block gld_lds DMA stream
//   sustains only ~8 B/cyc/CU; this bypasses the DMA entirely:
//     window it: ds_write tile(it+1) from regs (loaded last window,
//     16B/lane coalesced) -> issue global_load for tile(it+2) -> compute.
//   Reg buffers are PARITY-NAMED (k0/v0/k1/v1) with a hand-unrolled x2
//   loop so every access is compile-time (rule #20).
// LDS: 2 slots x 32KB @0; osh 64x132 f32 @65536; rsh @99328 (100352 B).
// ---------------------------------------------------------------------------
template <bool FAST>
__global__ __launch_bounds__(1024, 4) void mlstm_fwd_kernel(
    const float* __restrict__ qg, const float* __restrict__ kxg,
    const float* __restrict__ vg,
    const u16* __restrict__ kbf, const u16* __restrict__ vtbf,
    const float* __restrict__ ag, const float* __restrict__ cg,
    const float* __restrict__ fcg, float* __restrict__ out)
{
  const int bx = (int)blockIdx.x;
  const int bh = bx & 15, p = bx >> 4;
  const int tid = (int)threadIdx.x;
  const int w = tid >> 6, lane = tid & 63;
  const int quad = lane >> 4, l16 = lane & 15;
  const int kg = w & 3, rq = w >> 2;

  const int qtA = 31 - p, qtB = p;
  const int nA = qtA + 1;                 // nA + (qtB+1) == 33 for all p

  __shared__ __align__(16) unsigned char SM[100352];
  u16* Kst = (u16*)SM;                    // slot s: K @ s*16384(u16), V @ +8192
  float* osh = (float*)(SM + 65536);
  float* rsh = (float*)(SM + 99328);

  const size_t hoff = (size_t)bh * T_SEQ * DHEAD;
  const int goff = bh * T_SEQ;

  // Q -> B-frags qf[kc]: B[k=quad*8+j][n=l16], row = qt*64 + rq*16 + l16
  bf16x8 qf[4];
  auto loadQ = [&](int lqt) {
    const float* qp = qg + hoff + (size_t)(lqt * 64 + rq * 16 + l16) * DHEAD + quad * 8;
#pragma unroll
    for (int kc = 0; kc < 4; ++kc) {
      const float4 x0 = *(const float4*)(qp + kc * 32);
      const float4 x1 = *(const float4*)(qp + kc * 32 + 4);
      u16x8 t;
      t[0] = f2bfu(x0.x); t[1] = f2bfu(x0.y); t[2] = f2bfu(x0.z); t[3] = f2bfu(x0.w);
      t[4] = f2bfu(x1.x); t[5] = f2bfu(x1.y); t[6] = f2bfu(x1.z); t[7] = f2bfu(x1.w);
      qf[kc] = __builtin_bit_cast(bf16x8, t);
    }
  };

  f32x4 oa[8];                           // O^T partial: 8 vd-tiles x 16 rows
  float rsacc;
  auto zeroAcc = [&]() {
#pragma unroll
    for (int mt = 0; mt < 8; ++mt) oa[mt] = (f32x4){0.f, 0.f, 0.f, 0.f};
    rsacc = 0.f;
  };
  zeroAcc();

  // ---- staging addresses (loop-invariant) ----
  const int skey = tid >> 4, sdb = (tid & 15) ^ (skey & 7);
  const u16* ksBase = kbf + (size_t)goff * DHEAD + (size_t)skey * DHEAD + sdb * 8;
  const int svn = tid >> 3, svk = (tid & 7) ^ (svn & 7);
  const u16* vsBase = vtbf + (size_t)bh * DHEAD * T_SEQ + (size_t)svn * T_SEQ + svk * 8;

  auto stp = [&](int s) { return s < nA ? s : s - nA; };

  // issue global->reg loads for seq s (FAST only; 16B/lane coalesced)
  auto ld = [&](int s, u16x8& kr, u16x8& vr) {
    if (FAST) {
      const int st = stp(s);
      kr = *(const u16x8*)(ksBase + (size_t)st * 64 * DHEAD);
      vr = *(const u16x8*)(vsBase + st * 64);
    }
  };
  // write seq s into slot base KbL (reg data for FAST; full convert for slow)
  auto wr = [&](int s, u16x8 kr, u16x8 vr, u16* KbL) {
    if (FAST) {
      *(u16x8*)(KbL + tid * 8) = kr;
      *(u16x8*)(KbL + 8192 + tid * 8) = vr;
    } else {
      const int st = stp(s);
      const float ct = cg[goff + st * 64 + 63];
      const float* kp = kxg + hoff + (size_t)(st * 64 + skey) * DHEAD + sdb * 8;
      const float* vp = vg + hoff + (size_t)(st * 64) * DHEAD;
      const float scv = __expf(ag[goff + st * 64 + skey] - ct);
      const float4 x0 = *(const float4*)kp;
      const float4 x1 = *(const float4*)(kp + 4);
      u16x8 pk;
      pk[0] = f2bfu(x0.x * scv); pk[1] = f2bfu(x0.y * scv);
      pk[2] = f2bfu(x0.z * scv); pk[3] = f2bfu(x0.w * scv);
      pk[4] = f2bfu(x1.x * scv); pk[5] = f2bfu(x1.y * scv);
      pk[6] = f2bfu(x1.z * scv); pk[7] = f2bfu(x1.w * scv);
      *(u16x8*)(KbL + tid * 8) = pk;
      u16x8 pw;
#pragma unroll
      for (int rr = 0; rr < 8; ++rr)
        pw[rr] = f2bfu(vp[(size_t)(svk * 8 + rr) * DHEAD + svn]);
      *(u16x8*)(KbL + 8192 + tid * 8) = pw;
    }
  };

  const int keyA = kg * 16 + l16;         // A-frag key row (QK)
  const int ksw  = l16 & 7;
  // vd&7 == l16&7 for all mt -> V swizzle is mt-invariant:
  const int vbase = l16 * 64 + (((kg * 2 + (quad >> 1)) ^ (l16 & 7)) * 8) + (quad & 1) * 4;

  auto computeStage = [&](int cqt, int st, const u16* KbL, float ccmax) {
    const u16* VbL = KbL + 8192;

    // ---- S^T = K_hat Q^T ----
    f32x4 sa = (f32x4){0.f, 0.f, 0.f, 0.f};
#pragma unroll
    for (int kc = 0; kc < 4; ++kc) {
      const bf16x8 kf = ldsFrag(KbL + keyA * 128 + (((kc * 4 + quad) ^ ksw) * 8));
      sa = __builtin_amdgcn_mfma_f32_16x16x32_bf16(kf, qf[kc], sa, 0, 0, 0);
    }

    const float etile = SCALE * __expf(cg[goff + st * 64 + 63] - ccmax);
    float x0 = sa[0] * etile, x1 = sa[1] * etile;
    float x2 = sa[2] * etile, x3 = sa[3] * etile;
    if (st == cqt) {
      const int qr = rq * 16 + l16, kb0 = kg * 16 + quad * 4;
      if (kb0 + 0 > qr) x0 = 0.f;
      if (kb0 + 1 > qr) x1 = 0.f;
      if (kb0 + 2 > qr) x2 = 0.f;
      if (kb0 + 3 > qr) x3 = 0.f;
    }
    rsacc += (x0 + x1) + (x2 + x3);
    u32 plo, phi;
    asm("v_cvt_pk_bf16_f32 %0, %1, %2" : "=v"(plo) : "v"(x0), "v"(x1));
    asm("v_cvt_pk_bf16_f32 %0, %1, %2" : "=v"(phi) : "v"(x2), "v"(x3));
    const s16x4 pfr = __builtin_bit_cast(s16x4, (u32x2){plo, phi});

    // ---- O^T += V^T P^T ----
#pragma unroll
    for (int mt = 0; mt < 8; ++mt) {
      const s16x4 va = *(const s16x4*)(VbL + vbase + mt * 1024);
      oa[mt] = mfma16x16x16bf16(va, pfr, oa[mt]);
    }
  };

  auto epilogue = [&](int eqt, float ecmax) {
    float x = rsacc;
    x += __shfl_xor(x, 16, 64);
    x += __shfl_xor(x, 32, 64);
    if (lane < 16) rsh[kg * 64 + rq * 16 + lane] = x;
    __syncthreads();
    float inv = 0.f;
    if (kg == 3) {
      const int row = rq * 16 + l16;
      const float tot = rsh[row] + rsh[64 + row] + rsh[128 + row] + rsh[192 + row];
      const float nf = __expf(-(ecmax + fcg[goff + eqt * 64 + row]));
      inv = 1.f / fmaxf(fabsf(tot), nf);
    }
    for (int r = 0; r < 4; ++r) {
      if (kg == r) {
        const int row = rq * 16 + l16;
#pragma unroll
        for (int mt = 0; mt < 8; ++mt) {
          float* ap = osh + row * 132 + mt * 16 + quad * 4;
          f32x4 vv = oa[mt];
          if (r > 0) vv = vv + *(const f32x4*)ap;
          if (r == 3) vv = vv * inv;
          *(f32x4*)ap = vv;
        }
      }
      __syncthreads();
    }
    const int col = tid & 31, r0 = tid >> 5;
#pragma unroll
    for (int i = 0; i < 2; ++i) {
      const int row = r0 + 32 * i;
      const f32x4 vv = *(const f32x4*)(osh + row * 132 + col * 4);
      *(f32x4*)(out + hoff + (size_t)(eqt * 64 + row) * DHEAD + col * 4) = vv;
    }
    __syncthreads();
  };

  // -------- prologue --------
  int qt = qtA;
  float cmax = cg[goff + qtA * 64 + 63];
  loadQ(qtA);
  u16x8 k0, v0, k1, v1;                   // parity-named staging buffers
  ld(0, k0, v0);
  wr(0, k0, v0, Kst);                     // slot 0
  ld(1, k1, v1);
  __syncthreads();

  // transition helper (runs after the window whose it == nA-1)
  auto maybeTransition = [&](int it) {
    if (it == nA - 1) {
      loadQ(qtB);                         // qf is 16 regs: safe co-live (R1)
      epilogue(qtA, cmax);
      zeroAcc();
      qt = qtB;
      cmax = cg[goff + qtB * 64 + 63];
    }
  };

  // -------- 33 uniform windows, hand-unrolled x2 for parity-static regs ----
  for (int g = 0; g < 17; ++g) {
    {                                      // even window it = 2g, slot 0
      const int it = 2 * g;
      if (it < 32) wr(it + 1, k1, v1, Kst + 16384);   // slot 1
      if (it + 2 < 33) ld(it + 2, k0, v0);
      computeStage(qt, stp(it), Kst, cmax);
      __syncthreads();
      maybeTransition(it);
    }
    if (2 * g + 1 < 33) {                  // odd window it = 2g+1, slot 1
      const int it = 2 * g + 1;
      if (it < 32) wr(it + 1, k0, v0, Kst);           // slot 0
      if (it + 2 < 33) ld(it + 2, k1, v1);
      computeStage(qt, stp(it), Kst + 16384, cmax);
      __syncthreads();
      maybeTransition(it);
    }
  }
  epilogue(qtB, cmax);
}

// ---------------------------------------------------------------------------
extern "C" void kernel_launch(void* const* d_in, const int* in_sizes, int n_in,
                              void* d_out, int out_size, void* d_ws, size_t ws_size,
                              hipStream_t stream) {
  const float* q  = (const float*)d_in[0];
  const float* k  = (const float*)d_in[1];
  const float* v  = (const float*)d_in[2];
  const float* ig = (const float*)d_in[3];
  const float* fg = (const float*)d_in[4];

  const size_t gate_bytes = (size_t)3 * NBH * T_SEQ * sizeof(float);
  const size_t kv_elems   = (size_t)NBH * T_SEQ * DHEAD;
  const bool fast = ws_size >= gate_bytes + 2 * kv_elems * sizeof(u16);

  float* a_ws  = (float*)d_ws;
  float* c_ws  = a_ws + NBH * T_SEQ;
  float* fc_ws = c_ws + NBH * T_SEQ;
  u16* kbf  = (u16*)((char*)d_ws + gate_bytes);
  u16* vtbf = kbf + kv_elems;

  gate_scan_kernel<<<dim3(NBH), dim3(1024), 0, stream>>>(ig, fg, a_ws, c_ws, fc_ws);
  if (fast) {
    cvt_kv_kernel<<<dim3(T_SEQ / 64, NBH), dim3(256), 0, stream>>>(
        k, v, a_ws, c_ws, kbf, vtbf);
    mlstm_fwd_kernel<true><<<dim3(256), dim3(1024), 0, stream>>>(
        q, k, v, kbf, vtbf, a_ws, c_ws, fc_ws, (float*)d_out);
  } else {
    mlstm_fwd_kernel<false><<<dim3(256), dim3(1024), 0, stream>>>(
        q, k, v, kbf, vtbf, a_ws, c_ws, fc_ws, (float*)d_out);
  }
}